// Round 8
// baseline (608.774 us; speedup 1.0000x reference)
//
#include <hip/hip_runtime.h>
#include <hip/hip_bf16.h>

#define NN 50000
#define NE 800000
#define NB 782      // buckets of 64 nodes: b = dst >> 6
#define BCAP 1536   // mean 1023, sigma 32 -> 16-sigma margin
#define OVFCAP 4096

typedef __attribute__((ext_vector_type(8))) _Float16 half8v;
typedef __attribute__((ext_vector_type(4))) _Float16 half4v;
typedef __attribute__((ext_vector_type(2))) _Float16 half2v;
typedef __attribute__((ext_vector_type(4))) float f32x4;

__device__ __forceinline__ void gload_lds16(const void* g, void* l) {
  __builtin_amdgcn_global_load_lds((const __attribute__((address_space(1))) void*)g,
                                   (__attribute__((address_space(3))) void*)l, 16, 0, 0);
}
__device__ __forceinline__ void vm_wait5() {
  asm volatile("s_waitcnt vmcnt(5)" ::: "memory");
  __builtin_amdgcn_sched_barrier(0);
}
__device__ __forceinline__ void vm_wait0() {
  asm volatile("s_waitcnt vmcnt(0)" ::: "memory");
  __builtin_amdgcn_sched_barrier(0);
}
__device__ __forceinline__ void barx() {
  __builtin_amdgcn_sched_barrier(0);
  __builtin_amdgcn_s_barrier();
  __builtin_amdgcn_sched_barrier(0);
}

// ---------------- CSR build (bucketed, locality-aware) ----------------
__global__ void k_zero(int* __restrict__ p, int n) {
  int i = blockIdx.x * blockDim.x + threadIdx.x;
  if (i < n) p[i] = 0;
}

// Pass 1: scatter edges into per-bucket arrays. Packed pair = (src<<6)|(dst&63).
// Bucket cursor atomics give adjacent slots -> full-line write coalescing.
__global__ void k_radix(const int* __restrict__ src, const int* __restrict__ dst,
                        int* __restrict__ bcur, uint* __restrict__ pairs,
                        int* __restrict__ cnt, int* __restrict__ ovfn,
                        uint* __restrict__ ovf) {
  int t = blockIdx.x * blockDim.x + threadIdx.x;
  if (t * 4 >= NE) return;
  int4 s4 = reinterpret_cast<const int4*>(src)[t];
  int4 d4 = reinterpret_cast<const int4*>(dst)[t];
  int ss[4] = {s4.x, s4.y, s4.z, s4.w};
  int dd[4] = {d4.x, d4.y, d4.z, d4.w};
#pragma unroll
  for (int j = 0; j < 4; ++j) {
    int b = dd[j] >> 6;
    int p = atomicAdd(&bcur[b], 1);
    if (p < BCAP) {
      pairs[(size_t)b * BCAP + p] = ((uint)ss[j] << 6) | (uint)(dd[j] & 63);
    } else {  // practically never (16-sigma); correctness fallback
      int oi = atomicAdd(ovfn, 1);
      if (oi < OVFCAP) ovf[oi] = ((uint)dd[j] << 16) | (uint)ss[j];
      atomicAdd(&cnt[dd[j]], 1);
    }
  }
}

// Pass 2: per-bucket LDS histogram -> cnt (buckets partition nodes; one add/node)
__global__ __launch_bounds__(256) void k_countb(const int* __restrict__ bcur,
                                                const uint* __restrict__ pairs,
                                                int* __restrict__ cnt) {
  __shared__ int lc[64];
  const int b = blockIdx.x;
  if (threadIdx.x < 64) lc[threadIdx.x] = 0;
  __syncthreads();
  const int m = min(bcur[b], BCAP);
  for (int e = threadIdx.x; e < m; e += 256)
    atomicAdd(&lc[pairs[(size_t)b * BCAP + e] & 63], 1);
  __syncthreads();
  if (threadIdx.x < 64) {
    int node = b * 64 + threadIdx.x;
    int v = lc[threadIdx.x];
    if (node < NN && v) atomicAdd(&cnt[node], v);
  }
}

// exclusive scan of cnt -> rowptr; cnt becomes the fill cursor. 4 elems/thread.
__global__ __launch_bounds__(1024) void k_scan(int* __restrict__ cnt, int* __restrict__ rowptr) {
  __shared__ int wsum[16];
  __shared__ int woff[16];
  __shared__ int tot;
  const int tid = threadIdx.x;
  const int lane = tid & 63;
  const int w = tid >> 6;
  int running = 0;
  for (int base = 0; base < NN; base += 4096) {
    const int i4 = (base >> 2) + tid;
    int4 v = make_int4(0, 0, 0, 0);
    if (i4 * 4 < NN) v = reinterpret_cast<const int4*>(cnt)[i4];
    const int tsum = v.x + v.y + v.z + v.w;
    int x = tsum;
#pragma unroll
    for (int off = 1; off < 64; off <<= 1) {
      int t = __shfl_up(x, off);
      if (lane >= off) x += t;
    }
    if (lane == 63) wsum[w] = x;
    __syncthreads();
    if (w == 0) {
      int s = (lane < 16) ? wsum[lane] : 0;
#pragma unroll
      for (int off = 1; off < 16; off <<= 1) {
        int t = __shfl_up(s, off);
        if (lane >= off) s += t;
      }
      if (lane < 16) woff[lane] = s - wsum[lane];
      if (lane == 15) tot = s;
    }
    __syncthreads();
    if (i4 * 4 < NN) {
      int excl = running + woff[w] + (x - tsum);
      int4 r;
      r.x = excl;
      r.y = excl + v.x;
      r.z = r.y + v.y;
      r.w = r.z + v.z;
      reinterpret_cast<int4*>(rowptr)[i4] = r;
      reinterpret_cast<int4*>(cnt)[i4] = r;  // cursor copy
    }
    running += tot;
    __syncthreads();
  }
  if (tid == 0) rowptr[NN] = running;
}

// Pass 3: per-bucket fill; col writes land in one ~4KB contiguous region/bucket
__global__ __launch_bounds__(256) void k_fillb(const int* __restrict__ bcur,
                                               const uint* __restrict__ pairs,
                                               int* __restrict__ cursor,
                                               int* __restrict__ col) {
  const int b = blockIdx.x;
  const int m = min(bcur[b], BCAP);
  for (int e = threadIdx.x; e < m; e += 256) {
    uint u = pairs[(size_t)b * BCAP + e];
    int node = b * 64 + (int)(u & 63);
    int p = atomicAdd(&cursor[node], 1);
    col[p] = (int)(u >> 6);
  }
}

__global__ void k_fillovf(const int* __restrict__ ovfn, const uint* __restrict__ ovf,
                          int* __restrict__ cursor, int* __restrict__ col) {
  int n = min(*ovfn, OVFCAP);
  for (int i = threadIdx.x; i < n; i += 256) {
    uint u = ovf[i];
    int p = atomicAdd(&cursor[u >> 16], 1);
    col[p] = (int)(u & 0xFFFFu);
  }
}

// ---------------- weight pack: fragment-major fp16 ----------------
__global__ void k_wpack(const float* __restrict__ W, _Float16* __restrict__ Wp, int K) {
  int t = blockIdx.x * blockDim.x + threadIdx.x;
  if (t >= K * 32) return;
  int l = t & 63;
  int c = (t >> 6) & 15;
  int kb = t >> 10;
  int row = c * 16 + (l & 15);
  int k = kb * 32 + (l >> 4) * 8;
  half8v o;
#pragma unroll
  for (int i = 0; i < 8; ++i) o[i] = (_Float16)W[(size_t)(k + i) * 256 + row];
  *reinterpret_cast<half8v*>(Wp + (size_t)t * 8) = o;
}

// ---------------- x (fp32 [NN][128]) -> fp16 [NN][128] ----------------
__global__ void k_split16(const float* __restrict__ x, _Float16* __restrict__ X16) {
  int t = blockIdx.x * blockDim.x + threadIdx.x;
  if (t >= NN * 16) return;
  const float* p = x + (size_t)t * 8;
  float4 v0 = *reinterpret_cast<const float4*>(p);
  float4 v1 = *reinterpret_cast<const float4*>(p + 4);
  half8v o;
  o[0] = (_Float16)v0.x; o[1] = (_Float16)v0.y; o[2] = (_Float16)v0.z; o[3] = (_Float16)v0.w;
  o[4] = (_Float16)v1.x; o[5] = (_Float16)v1.y; o[6] = (_Float16)v1.z; o[7] = (_Float16)v1.w;
  *reinterpret_cast<half8v*>(X16 + (size_t)t * 8) = o;
}

// ---------------- aggregation: fp32 x (D=128) -> fp16 N [NN][128] ----------------
__global__ __launch_bounds__(256) void k_agg_x16(const float* __restrict__ x,
                                                 const int* __restrict__ rowptr,
                                                 const int* __restrict__ col,
                                                 _Float16* __restrict__ N) {
  const int lane = threadIdx.x & 63;
  const int n = blockIdx.x * 4 + (threadIdx.x >> 6);
  if (n >= NN) return;
  const int start = rowptr[n];
  const int end = rowptr[n + 1];
  float a0 = 0.f, a1 = 0.f;
  for (int base = start; base < end; base += 64) {
    int e = base + lane;
    int c = (e < end) ? col[e] : 0;
    int m = min(64, end - base);
    int t = 0;
    for (; t + 3 < m; t += 4) {
      int c0 = __shfl(c, t), c1 = __shfl(c, t + 1), c2 = __shfl(c, t + 2), c3 = __shfl(c, t + 3);
      float2 v0 = *reinterpret_cast<const float2*>(x + (size_t)c0 * 128 + lane * 2);
      float2 v1 = *reinterpret_cast<const float2*>(x + (size_t)c1 * 128 + lane * 2);
      float2 v2 = *reinterpret_cast<const float2*>(x + (size_t)c2 * 128 + lane * 2);
      float2 v3 = *reinterpret_cast<const float2*>(x + (size_t)c3 * 128 + lane * 2);
      a0 += v0.x + v1.x + v2.x + v3.x;
      a1 += v0.y + v1.y + v2.y + v3.y;
    }
    for (; t < m; ++t) {
      int cs = __shfl(c, t);
      float2 v = *reinterpret_cast<const float2*>(x + (size_t)cs * 128 + lane * 2);
      a0 += v.x;
      a1 += v.y;
    }
  }
  int deg = end - start;
  float sc = 1.0f / (float)(deg > 0 ? deg : 1);
  half2v o;
  o[0] = (_Float16)(a0 * sc);
  o[1] = (_Float16)(a1 * sc);
  *reinterpret_cast<half2v*>(N + (size_t)n * 128 + lane * 2) = o;
}

// ---------------- aggregation: fp16 H (D=256) -> fp16 N [NN][256] ----------------
__global__ __launch_bounds__(256) void k_agg16(const _Float16* __restrict__ H,
                                               const int* __restrict__ rowptr,
                                               const int* __restrict__ col,
                                               _Float16* __restrict__ N) {
  const int lane = threadIdx.x & 63;
  const int n = blockIdx.x * 4 + (threadIdx.x >> 6);
  if (n >= NN) return;
  const int start = rowptr[n];
  const int end = rowptr[n + 1];
  float a0 = 0.f, a1 = 0.f, a2 = 0.f, a3 = 0.f;
  for (int base = start; base < end; base += 64) {
    int e = base + lane;
    int c = (e < end) ? col[e] : 0;
    int m = min(64, end - base);
    int t = 0;
    for (; t + 3 < m; t += 4) {
      int c0 = __shfl(c, t), c1 = __shfl(c, t + 1), c2 = __shfl(c, t + 2), c3 = __shfl(c, t + 3);
      half4v v0 = *reinterpret_cast<const half4v*>(H + (size_t)c0 * 256 + lane * 4);
      half4v v1 = *reinterpret_cast<const half4v*>(H + (size_t)c1 * 256 + lane * 4);
      half4v v2 = *reinterpret_cast<const half4v*>(H + (size_t)c2 * 256 + lane * 4);
      half4v v3 = *reinterpret_cast<const half4v*>(H + (size_t)c3 * 256 + lane * 4);
      a0 += (float)v0[0] + (float)v1[0] + (float)v2[0] + (float)v3[0];
      a1 += (float)v0[1] + (float)v1[1] + (float)v2[1] + (float)v3[1];
      a2 += (float)v0[2] + (float)v1[2] + (float)v2[2] + (float)v3[2];
      a3 += (float)v0[3] + (float)v1[3] + (float)v2[3] + (float)v3[3];
    }
    for (; t < m; ++t) {
      int cs = __shfl(c, t);
      half4v v = *reinterpret_cast<const half4v*>(H + (size_t)cs * 256 + lane * 4);
      a0 += (float)v[0];
      a1 += (float)v[1];
      a2 += (float)v[2];
      a3 += (float)v[3];
    }
  }
  int deg = end - start;
  float sc = 1.0f / (float)(deg > 0 ? deg : 1);
  half4v o;
  o[0] = (_Float16)(a0 * sc);
  o[1] = (_Float16)(a1 * sc);
  o[2] = (_Float16)(a2 * sc);
  o[3] = (_Float16)(a3 * sc);
  *reinterpret_cast<half4v*>(N + (size_t)n * 256 + lane * 4) = o;
}

// ---------------- fp16 MFMA dual-GEMM, counted-vmcnt pipeline (R7, unchanged) ----
__global__ __launch_bounds__(256) void k_mfma16(
    const _Float16* __restrict__ A1, const _Float16* __restrict__ A2,
    const _Float16* __restrict__ W1p, const _Float16* __restrict__ W2p,
    const float* __restrict__ bias, int K,
    _Float16* __restrict__ outH, float* __restrict__ outF) {
  __shared__ _Float16 LDS[20480];  // 40 KB: 2 pipeline bufs; reused as 64x264 out tile
  const int tid = threadIdx.x;
  const int w = tid >> 6;
  const int lane = tid & 63;
  const int lrow = lane & 15;
  const int kg8 = (lane >> 4) * 8;
  const int m0 = blockIdx.x * 64;
  const int nk = K >> 5;
  const int nsteps = nk * 2;

  f32x4 acc[4][4];
#pragma unroll
  for (int i = 0; i < 4; ++i)
#pragma unroll
    for (int j = 0; j < 4; ++j) acc[i][j] = (f32x4){0.f, 0.f, 0.f, 0.f};

  int arowi = m0 + w * 16 + lrow;
  const size_t arow = (size_t)(arowi < NN ? arowi : NN - 1);

#define STAGE(S, B)                                                            \
  {                                                                            \
    const _Float16* Ap = ((S) >= nk) ? A2 : A1;                                \
    const _Float16* Wp = ((S) >= nk) ? W2p : W1p;                              \
    const int sl = ((S) >= nk) ? (S) - nk : (S);                               \
    gload_lds16(Ap + arow * K + (sl << 5) + kg8,                               \
                (void*)&LDS[(B) * 10240 + w * 512]);                           \
    const _Float16* wsrc = Wp + (size_t)(sl * 16 + w * 4) * 512 + lane * 8;    \
    _Pragma("unroll") for (int j = 0; j < 4; ++j)                              \
        gload_lds16(wsrc + j * 512,                                            \
                    (void*)&LDS[(B) * 10240 + 2048 + (w * 4 + j) * 512]);      \
  }

#define COMPUTE(B)                                                             \
  {                                                                            \
    half8v af[4];                                                              \
    _Pragma("unroll") for (int rf = 0; rf < 4; ++rf)                           \
        af[rf] = *reinterpret_cast<const half8v*>(                             \
            &LDS[(B) * 10240 + rf * 512 + lane * 8]);                          \
    _Pragma("unroll") for (int cf = 0; cf < 4; ++cf) {                         \
      half8v bf = *reinterpret_cast<const half8v*>(                            \
          &LDS[(B) * 10240 + 2048 + (w * 4 + cf) * 512 + lane * 8]);           \
      _Pragma("unroll") for (int rf = 0; rf < 4; ++rf)                         \
          acc[rf][cf] = __builtin_amdgcn_mfma_f32_16x16x32_f16(                \
              af[rf], bf, acc[rf][cf], 0, 0, 0);                               \
    }                                                                          \
  }

  STAGE(0, 0);
  STAGE(1, 1);
  vm_wait5();
  barx();
  for (int s = 0; s < nsteps; ++s) {
    COMPUTE(s & 1);
    barx();
    if (s + 2 < nsteps) {
      STAGE(s + 2, s & 1);
      vm_wait5();
    } else {
      vm_wait0();
    }
    barx();
  }
#undef STAGE
#undef COMPUTE

  const int rquad = (lane >> 4) * 4;
  if (outF) {
#pragma unroll
    for (int cf = 0; cf < 4; ++cf) {
      const int colc = w * 64 + cf * 16 + lrow;
      const float bb = bias[colc];
#pragma unroll
      for (int rf = 0; rf < 4; ++rf)
#pragma unroll
        for (int j = 0; j < 4; ++j) {
          const int row = m0 + rf * 16 + rquad + j;
          if (row < NN) {
            float v = acc[rf][cf][j] + bb;
            outF[(size_t)row * 256 + colc] = v > 0.f ? v : 0.f;
          }
        }
    }
  } else {
#pragma unroll
    for (int cf = 0; cf < 4; ++cf) {
      const int colc = w * 64 + cf * 16 + lrow;
      const float bb = bias[colc];
#pragma unroll
      for (int rf = 0; rf < 4; ++rf)
#pragma unroll
        for (int j = 0; j < 4; ++j) {
          float v = acc[rf][cf][j] + bb;
          LDS[(rf * 16 + rquad + j) * 264 + colc] = (_Float16)(v > 0.f ? v : 0.f);
        }
    }
    __syncthreads();
    const int row = tid >> 2;
    const int q = tid & 3;
    if (m0 + row < NN) {
#pragma unroll
      for (int it = 0; it < 8; ++it)
        *reinterpret_cast<half8v*>(outH + (size_t)(m0 + row) * 256 + q * 64 + it * 8) =
            *reinterpret_cast<const half8v*>(&LDS[row * 264 + q * 64 + it * 8]);
    }
  }
}

extern "C" void kernel_launch(void* const* d_in, const int* in_sizes, int n_in,
                              void* d_out, int out_size, void* d_ws, size_t ws_size,
                              hipStream_t stream) {
  const float* x   = (const float*)d_in[0];
  const int* src   = (const int*)d_in[1];
  const int* dst   = (const int*)d_in[2];
  const float* Ws0 = (const float*)d_in[3];
  const float* Wn0 = (const float*)d_in[4];
  const float* b0  = (const float*)d_in[5];
  const float* Ws1 = (const float*)d_in[6];
  const float* Wn1 = (const float*)d_in[7];
  const float* b1  = (const float*)d_in[8];
  const float* Ws2 = (const float*)d_in[9];
  const float* Wn2 = (const float*)d_in[10];
  const float* b2  = (const float*)d_in[11];
  float* out = (float*)d_out;

  char* ws = (char*)d_ws;
  size_t off = 0;
  auto alloc = [&](size_t bytes) {
    void* p = ws + off;
    off = (off + bytes + 255) & ~(size_t)255;
    return p;
  };
  _Float16* X16 = (_Float16*)alloc((size_t)NN * 128 * 2);
  _Float16* H   = (_Float16*)alloc((size_t)NN * 256 * 2);
  _Float16* Nb  = (_Float16*)alloc((size_t)NN * 256 * 2);
  int* rowptr = (int*)alloc((size_t)(NN + 1) * sizeof(int));
  // meta block: cnt[50048 pad] | bcur[1024 pad] | ovfn[64]
  const int ZN = 50048 + 1024 + 64;
  int* meta = (int*)alloc((size_t)ZN * sizeof(int));
  int* cnt  = meta;
  int* bcur = meta + 50048;
  int* ovfn = meta + 50048 + 1024;
  int* col    = (int*)alloc((size_t)NE * sizeof(int));
  uint* pairs = (uint*)alloc((size_t)NB * BCAP * sizeof(uint));
  uint* ovf   = (uint*)alloc((size_t)OVFCAP * sizeof(uint));
  _Float16* W0s = (_Float16*)alloc(256 * 128 * 2);
  _Float16* W0n = (_Float16*)alloc(256 * 128 * 2);
  _Float16* W1s = (_Float16*)alloc(256 * 256 * 2);
  _Float16* W1n = (_Float16*)alloc(256 * 256 * 2);
  _Float16* W2s = (_Float16*)alloc(256 * 256 * 2);
  _Float16* W2n = (_Float16*)alloc(256 * 256 * 2);

  // CSR build (bucketed)
  k_zero<<<(ZN + 1023) / 1024, 1024, 0, stream>>>(meta, ZN);
  k_radix<<<(NE / 4 + 255) / 256, 256, 0, stream>>>(src, dst, bcur, pairs, cnt, ovfn, ovf);
  k_countb<<<NB, 256, 0, stream>>>(bcur, pairs, cnt);
  k_scan<<<1, 1024, 0, stream>>>(cnt, rowptr);
  k_fillb<<<NB, 256, 0, stream>>>(bcur, pairs, cnt, col);
  k_fillovf<<<1, 256, 0, stream>>>(ovfn, ovf, cnt, col);

  // weight prep (fragment-major pack, fp16)
  k_wpack<<<16, 256, 0, stream>>>(Ws0, W0s, 128);
  k_wpack<<<16, 256, 0, stream>>>(Wn0, W0n, 128);
  k_wpack<<<32, 256, 0, stream>>>(Ws1, W1s, 256);
  k_wpack<<<32, 256, 0, stream>>>(Wn1, W1n, 256);
  k_wpack<<<32, 256, 0, stream>>>(Ws2, W2s, 256);
  k_wpack<<<32, 256, 0, stream>>>(Wn2, W2n, 256);

  // x -> fp16
  k_split16<<<(NN * 16 + 255) / 256, 256, 0, stream>>>(x, X16);

  const int aggGrid = (NN + 3) / 4;
  const int gemmGrid = (NN + 63) / 64;

  // layer 0 (K=128)
  k_agg_x16<<<aggGrid, 256, 0, stream>>>(x, rowptr, col, Nb);
  k_mfma16<<<gemmGrid, 256, 0, stream>>>(X16, Nb, W0s, W0n, b0, 128, H, nullptr);
  // layer 1 (K=256)
  k_agg16<<<aggGrid, 256, 0, stream>>>(H, rowptr, col, Nb);
  k_mfma16<<<gemmGrid, 256, 0, stream>>>(H, Nb, W1s, W1n, b1, 256, H, nullptr);
  // layer 2 (K=256) -> fp32 out
  k_agg16<<<aggGrid, 256, 0, stream>>>(H, rowptr, col, Nb);
  k_mfma16<<<gemmGrid, 256, 0, stream>>>(H, Nb, W2s, W2n, b2, 256, nullptr, out);
}

// Round 10
// 433.684 us; speedup vs baseline: 1.4037x; 1.4037x over previous
//
#include <hip/hip_runtime.h>
#include <hip/hip_bf16.h>

#define NN 50000
#define NE 800000
#define NB 782      // buckets of 64 nodes: b = dst >> 6
#define BCAP 1536   // mean 1023, sigma 32 -> 16-sigma margin
#define OVFCAP 4096
#define RADIX_BLOCKS 128

typedef __attribute__((ext_vector_type(8))) _Float16 half8v;
typedef __attribute__((ext_vector_type(4))) _Float16 half4v;
typedef __attribute__((ext_vector_type(2))) _Float16 half2v;
typedef __attribute__((ext_vector_type(4))) float f32x4;

__device__ __forceinline__ void gload_lds16(const void* g, void* l) {
  __builtin_amdgcn_global_load_lds((const __attribute__((address_space(1))) void*)g,
                                   (__attribute__((address_space(3))) void*)l, 16, 0, 0);
}
__device__ __forceinline__ void vm_wait5() {
  asm volatile("s_waitcnt vmcnt(5)" ::: "memory");
  __builtin_amdgcn_sched_barrier(0);
}
__device__ __forceinline__ void vm_wait0() {
  asm volatile("s_waitcnt vmcnt(0)" ::: "memory");
  __builtin_amdgcn_sched_barrier(0);
}
__device__ __forceinline__ void barx() {
  __builtin_amdgcn_sched_barrier(0);
  __builtin_amdgcn_s_barrier();
  __builtin_amdgcn_sched_barrier(0);
}

// ---------------- CSR build (bucketed, LDS-privatized radix) ----------------
__global__ void k_zero(int* __restrict__ p, int n) {
  int i = blockIdx.x * blockDim.x + threadIdx.x;
  if (i < n) p[i] = 0;
}

// Pass 1: partition edges into per-bucket arrays, block-privatized histogram.
// Per block: LDS hist -> one global atomic per non-empty bucket (range reserve)
// -> placement via LDS cursors. Packed pair = (src<<6)|(dst&63).
__global__ __launch_bounds__(256) void k_radix(const int* __restrict__ src,
                                               const int* __restrict__ dst,
                                               int* __restrict__ bcur,
                                               uint* __restrict__ pairs,
                                               int* __restrict__ cnt,
                                               int* __restrict__ ovfn,
                                               uint* __restrict__ ovf) {
  __shared__ int hist[NB];
  __shared__ int lbase[NB];
  const int tid = threadIdx.x;
  const int chunk = (NE + RADIX_BLOCKS - 1) / RADIX_BLOCKS;
  const int e0 = blockIdx.x * chunk;
  const int e1 = min(e0 + chunk, NE);
  for (int i = tid; i < NB; i += 256) hist[i] = 0;
  __syncthreads();
  for (int e = e0 + tid; e < e1; e += 256) atomicAdd(&hist[dst[e] >> 6], 1);
  __syncthreads();
  for (int i = tid; i < NB; i += 256) {
    int h = hist[i];
    lbase[i] = h ? atomicAdd(&bcur[i], h) : 0;
    hist[i] = 0;  // reuse as block-local cursor
  }
  __syncthreads();
  for (int e = e0 + tid; e < e1; e += 256) {
    int d = dst[e], s = src[e];
    int b = d >> 6;
    int p = lbase[b] + atomicAdd(&hist[b], 1);
    if (p < BCAP) {
      pairs[(size_t)b * BCAP + p] = ((uint)s << 6) | (uint)(d & 63);
    } else {  // 16-sigma fallback
      int oi = atomicAdd(ovfn, 1);
      if (oi < OVFCAP) ovf[oi] = ((uint)d << 16) | (uint)s;
      atomicAdd(&cnt[d], 1);
    }
  }
}

// Pass 2: per-bucket LDS histogram -> cnt (buckets partition nodes)
__global__ __launch_bounds__(256) void k_countb(const int* __restrict__ bcur,
                                                const uint* __restrict__ pairs,
                                                int* __restrict__ cnt) {
  __shared__ int lc[64];
  const int b = blockIdx.x;
  if (threadIdx.x < 64) lc[threadIdx.x] = 0;
  __syncthreads();
  const int m = min(bcur[b], BCAP);
  for (int e = threadIdx.x; e < m; e += 256)
    atomicAdd(&lc[pairs[(size_t)b * BCAP + e] & 63], 1);
  __syncthreads();
  if (threadIdx.x < 64) {
    int node = b * 64 + threadIdx.x;
    int v = lc[threadIdx.x];
    if (node < NN && v) atomicAdd(&cnt[node], v);
  }
}

// exclusive scan of cnt -> rowptr; cnt becomes the fill cursor. 4 elems/thread.
__global__ __launch_bounds__(1024) void k_scan(int* __restrict__ cnt, int* __restrict__ rowptr) {
  __shared__ int wsum[16];
  __shared__ int woff[16];
  __shared__ int tot;
  const int tid = threadIdx.x;
  const int lane = tid & 63;
  const int w = tid >> 6;
  int running = 0;
  for (int base = 0; base < NN; base += 4096) {
    const int i4 = (base >> 2) + tid;
    int4 v = make_int4(0, 0, 0, 0);
    if (i4 * 4 < NN) v = reinterpret_cast<const int4*>(cnt)[i4];
    const int tsum = v.x + v.y + v.z + v.w;
    int x = tsum;
#pragma unroll
    for (int off = 1; off < 64; off <<= 1) {
      int t = __shfl_up(x, off);
      if (lane >= off) x += t;
    }
    if (lane == 63) wsum[w] = x;
    __syncthreads();
    if (w == 0) {
      int s = (lane < 16) ? wsum[lane] : 0;
#pragma unroll
      for (int off = 1; off < 16; off <<= 1) {
        int t = __shfl_up(s, off);
        if (lane >= off) s += t;
      }
      if (lane < 16) woff[lane] = s - wsum[lane];
      if (lane == 15) tot = s;
    }
    __syncthreads();
    if (i4 * 4 < NN) {
      int excl = running + woff[w] + (x - tsum);
      int4 r;
      r.x = excl;
      r.y = excl + v.x;
      r.z = r.y + v.y;
      r.w = r.z + v.z;
      reinterpret_cast<int4*>(rowptr)[i4] = r;
      reinterpret_cast<int4*>(cnt)[i4] = r;  // cursor copy
    }
    running += tot;
    __syncthreads();
  }
  if (tid == 0) rowptr[NN] = running;
}

// Pass 3: per-bucket fill; col writes land in one ~4KB contiguous region/bucket
__global__ __launch_bounds__(256) void k_fillb(const int* __restrict__ bcur,
                                               const uint* __restrict__ pairs,
                                               int* __restrict__ cursor,
                                               int* __restrict__ col) {
  const int b = blockIdx.x;
  const int m = min(bcur[b], BCAP);
  for (int e = threadIdx.x; e < m; e += 256) {
    uint u = pairs[(size_t)b * BCAP + e];
    int node = b * 64 + (int)(u & 63);
    int p = atomicAdd(&cursor[node], 1);
    col[p] = (int)(u >> 6);
  }
}

__global__ void k_fillovf(const int* __restrict__ ovfn, const uint* __restrict__ ovf,
                          int* __restrict__ cursor, int* __restrict__ col) {
  int n = min(*ovfn, OVFCAP);
  for (int i = threadIdx.x; i < n; i += 256) {
    uint u = ovf[i];
    int p = atomicAdd(&cursor[u >> 16], 1);
    col[p] = (int)(u & 0xFFFFu);
  }
}

// ---------------- weight pack: fragment-major fp16 ----------------
__global__ void k_wpack(const float* __restrict__ W, _Float16* __restrict__ Wp, int K) {
  int t = blockIdx.x * blockDim.x + threadIdx.x;
  if (t >= K * 32) return;
  int l = t & 63;
  int c = (t >> 6) & 15;
  int kb = t >> 10;
  int row = c * 16 + (l & 15);
  int k = kb * 32 + (l >> 4) * 8;
  half8v o;
#pragma unroll
  for (int i = 0; i < 8; ++i) o[i] = (_Float16)W[(size_t)(k + i) * 256 + row];
  *reinterpret_cast<half8v*>(Wp + (size_t)t * 8) = o;
}

// ---------------- x (fp32 [NN][128]) -> fp16 [NN][128] ----------------
__global__ void k_split16(const float* __restrict__ x, _Float16* __restrict__ X16) {
  int t = blockIdx.x * blockDim.x + threadIdx.x;
  if (t >= NN * 16) return;
  const float* p = x + (size_t)t * 8;
  float4 v0 = *reinterpret_cast<const float4*>(p);
  float4 v1 = *reinterpret_cast<const float4*>(p + 4);
  half8v o;
  o[0] = (_Float16)v0.x; o[1] = (_Float16)v0.y; o[2] = (_Float16)v0.z; o[3] = (_Float16)v0.w;
  o[4] = (_Float16)v1.x; o[5] = (_Float16)v1.y; o[6] = (_Float16)v1.z; o[7] = (_Float16)v1.w;
  *reinterpret_cast<half8v*>(X16 + (size_t)t * 8) = o;
}

// ---------------- aggregation: fp32 x (D=128) -> fp16 N [NN][128] ----------------
__global__ __launch_bounds__(256) void k_agg_x16(const float* __restrict__ x,
                                                 const int* __restrict__ rowptr,
                                                 const int* __restrict__ col,
                                                 _Float16* __restrict__ N) {
  const int lane = threadIdx.x & 63;
  const int n = blockIdx.x * 4 + (threadIdx.x >> 6);
  if (n >= NN) return;
  const int start = rowptr[n];
  const int end = rowptr[n + 1];
  float a0 = 0.f, a1 = 0.f;
  for (int base = start; base < end; base += 64) {
    int e = base + lane;
    int c = (e < end) ? col[e] : 0;
    int m = min(64, end - base);
    int t = 0;
    for (; t + 3 < m; t += 4) {
      int c0 = __shfl(c, t), c1 = __shfl(c, t + 1), c2 = __shfl(c, t + 2), c3 = __shfl(c, t + 3);
      float2 v0 = *reinterpret_cast<const float2*>(x + (size_t)c0 * 128 + lane * 2);
      float2 v1 = *reinterpret_cast<const float2*>(x + (size_t)c1 * 128 + lane * 2);
      float2 v2 = *reinterpret_cast<const float2*>(x + (size_t)c2 * 128 + lane * 2);
      float2 v3 = *reinterpret_cast<const float2*>(x + (size_t)c3 * 128 + lane * 2);
      a0 += v0.x + v1.x + v2.x + v3.x;
      a1 += v0.y + v1.y + v2.y + v3.y;
    }
    for (; t < m; ++t) {
      int cs = __shfl(c, t);
      float2 v = *reinterpret_cast<const float2*>(x + (size_t)cs * 128 + lane * 2);
      a0 += v.x;
      a1 += v.y;
    }
  }
  int deg = end - start;
  float sc = 1.0f / (float)(deg > 0 ? deg : 1);
  half2v o;
  o[0] = (_Float16)(a0 * sc);
  o[1] = (_Float16)(a1 * sc);
  *reinterpret_cast<half2v*>(N + (size_t)n * 128 + lane * 2) = o;
}

// ---------------- aggregation: fp16 H (D=256) -> fp16 N [NN][256] ----------------
__global__ __launch_bounds__(256) void k_agg16(const _Float16* __restrict__ H,
                                               const int* __restrict__ rowptr,
                                               const int* __restrict__ col,
                                               _Float16* __restrict__ N) {
  const int lane = threadIdx.x & 63;
  const int n = blockIdx.x * 4 + (threadIdx.x >> 6);
  if (n >= NN) return;
  const int start = rowptr[n];
  const int end = rowptr[n + 1];
  float a0 = 0.f, a1 = 0.f, a2 = 0.f, a3 = 0.f;
  for (int base = start; base < end; base += 64) {
    int e = base + lane;
    int c = (e < end) ? col[e] : 0;
    int m = min(64, end - base);
    int t = 0;
    for (; t + 3 < m; t += 4) {
      int c0 = __shfl(c, t), c1 = __shfl(c, t + 1), c2 = __shfl(c, t + 2), c3 = __shfl(c, t + 3);
      half4v v0 = *reinterpret_cast<const half4v*>(H + (size_t)c0 * 256 + lane * 4);
      half4v v1 = *reinterpret_cast<const half4v*>(H + (size_t)c1 * 256 + lane * 4);
      half4v v2 = *reinterpret_cast<const half4v*>(H + (size_t)c2 * 256 + lane * 4);
      half4v v3 = *reinterpret_cast<const half4v*>(H + (size_t)c3 * 256 + lane * 4);
      a0 += (float)v0[0] + (float)v1[0] + (float)v2[0] + (float)v3[0];
      a1 += (float)v0[1] + (float)v1[1] + (float)v2[1] + (float)v3[1];
      a2 += (float)v0[2] + (float)v1[2] + (float)v2[2] + (float)v3[2];
      a3 += (float)v0[3] + (float)v1[3] + (float)v2[3] + (float)v3[3];
    }
    for (; t < m; ++t) {
      int cs = __shfl(c, t);
      half4v v = *reinterpret_cast<const half4v*>(H + (size_t)cs * 256 + lane * 4);
      a0 += (float)v[0];
      a1 += (float)v[1];
      a2 += (float)v[2];
      a3 += (float)v[3];
    }
  }
  int deg = end - start;
  float sc = 1.0f / (float)(deg > 0 ? deg : 1);
  half4v o;
  o[0] = (_Float16)(a0 * sc);
  o[1] = (_Float16)(a1 * sc);
  o[2] = (_Float16)(a2 * sc);
  o[3] = (_Float16)(a3 * sc);
  *reinterpret_cast<half4v*>(N + (size_t)n * 256 + lane * 4) = o;
}

// ---------------- fp16 MFMA dual-GEMM, counted-vmcnt pipeline ----------------
__global__ __launch_bounds__(256) void k_mfma16(
    const _Float16* __restrict__ A1, const _Float16* __restrict__ A2,
    const _Float16* __restrict__ W1p, const _Float16* __restrict__ W2p,
    const float* __restrict__ bias, int K,
    _Float16* __restrict__ outH, float* __restrict__ outF) {
  __shared__ _Float16 LDS[20480];  // 40 KB: 2 pipeline bufs; reused as 64x264 out tile
  const int tid = threadIdx.x;
  const int w = tid >> 6;
  const int lane = tid & 63;
  const int lrow = lane & 15;
  const int kg8 = (lane >> 4) * 8;
  const int m0 = blockIdx.x * 64;
  const int nk = K >> 5;
  const int nsteps = nk * 2;

  f32x4 acc[4][4];
#pragma unroll
  for (int i = 0; i < 4; ++i)
#pragma unroll
    for (int j = 0; j < 4; ++j) acc[i][j] = (f32x4){0.f, 0.f, 0.f, 0.f};

  int arowi = m0 + w * 16 + lrow;
  const size_t arow = (size_t)(arowi < NN ? arowi : NN - 1);

#define STAGE(S, B)                                                            \
  {                                                                            \
    const _Float16* Ap = ((S) >= nk) ? A2 : A1;                                \
    const _Float16* Wp = ((S) >= nk) ? W2p : W1p;                              \
    const int sl = ((S) >= nk) ? (S) - nk : (S);                               \
    gload_lds16(Ap + arow * K + (sl << 5) + kg8,                               \
                (void*)&LDS[(B) * 10240 + w * 512]);                           \
    const _Float16* wsrc = Wp + (size_t)(sl * 16 + w * 4) * 512 + lane * 8;    \
    _Pragma("unroll") for (int j = 0; j < 4; ++j)                              \
        gload_lds16(wsrc + j * 512,                                            \
                    (void*)&LDS[(B) * 10240 + 2048 + (w * 4 + j) * 512]);      \
  }

#define COMPUTE(B)                                                             \
  {                                                                            \
    half8v af[4];                                                              \
    _Pragma("unroll") for (int rf = 0; rf < 4; ++rf)                           \
        af[rf] = *reinterpret_cast<const half8v*>(                             \
            &LDS[(B) * 10240 + rf * 512 + lane * 8]);                          \
    _Pragma("unroll") for (int cf = 0; cf < 4; ++cf) {                         \
      half8v bf = *reinterpret_cast<const half8v*>(                            \
          &LDS[(B) * 10240 + 2048 + (w * 4 + cf) * 512 + lane * 8]);           \
      _Pragma("unroll") for (int rf = 0; rf < 4; ++rf)                         \
          acc[rf][cf] = __builtin_amdgcn_mfma_f32_16x16x32_f16(                \
              af[rf], bf, acc[rf][cf], 0, 0, 0);                               \
    }                                                                          \
  }

  STAGE(0, 0);
  STAGE(1, 1);
  vm_wait5();
  barx();
  for (int s = 0; s < nsteps; ++s) {
    COMPUTE(s & 1);
    barx();
    if (s + 2 < nsteps) {
      STAGE(s + 2, s & 1);
      vm_wait5();
    } else {
      vm_wait0();
    }
    barx();
  }
#undef STAGE
#undef COMPUTE

  const int rquad = (lane >> 4) * 4;
  if (outF) {
#pragma unroll
    for (int cf = 0; cf < 4; ++cf) {
      const int colc = w * 64 + cf * 16 + lrow;
      const float bb = bias[colc];
#pragma unroll
      for (int rf = 0; rf < 4; ++rf)
#pragma unroll
        for (int j = 0; j < 4; ++j) {
          const int row = m0 + rf * 16 + rquad + j;
          if (row < NN) {
            float v = acc[rf][cf][j] + bb;
            outF[(size_t)row * 256 + colc] = v > 0.f ? v : 0.f;
          }
        }
    }
  } else {
#pragma unroll
    for (int cf = 0; cf < 4; ++cf) {
      const int colc = w * 64 + cf * 16 + lrow;
      const float bb = bias[colc];
#pragma unroll
      for (int rf = 0; rf < 4; ++rf)
#pragma unroll
        for (int j = 0; j < 4; ++j) {
          float v = acc[rf][cf][j] + bb;
          LDS[(rf * 16 + rquad + j) * 264 + colc] = (_Float16)(v > 0.f ? v : 0.f);
        }
    }
    __syncthreads();
    const int row = tid >> 2;
    const int q = tid & 3;
    if (m0 + row < NN) {
#pragma unroll
      for (int it = 0; it < 8; ++it)
        *reinterpret_cast<half8v*>(outH + (size_t)(m0 + row) * 256 + q * 64 + it * 8) =
            *reinterpret_cast<const half8v*>(&LDS[row * 264 + q * 64 + it * 8]);
    }
  }
}

extern "C" void kernel_launch(void* const* d_in, const int* in_sizes, int n_in,
                              void* d_out, int out_size, void* d_ws, size_t ws_size,
                              hipStream_t stream) {
  const float* x   = (const float*)d_in[0];
  const int* src   = (const int*)d_in[1];
  const int* dst   = (const int*)d_in[2];
  const float* Ws0 = (const float*)d_in[3];
  const float* Wn0 = (const float*)d_in[4];
  const float* b0  = (const float*)d_in[5];
  const float* Ws1 = (const float*)d_in[6];
  const float* Wn1 = (const float*)d_in[7];
  const float* b1  = (const float*)d_in[8];
  const float* Ws2 = (const float*)d_in[9];
  const float* Wn2 = (const float*)d_in[10];
  const float* b2  = (const float*)d_in[11];
  float* out = (float*)d_out;

  char* ws = (char*)d_ws;
  size_t off = 0;
  auto alloc = [&](size_t bytes) {
    void* p = ws + off;
    off = (off + bytes + 255) & ~(size_t)255;
    return p;
  };
  _Float16* X16 = (_Float16*)alloc((size_t)NN * 128 * 2);
  _Float16* H   = (_Float16*)alloc((size_t)NN * 256 * 2);
  _Float16* Nb  = (_Float16*)alloc((size_t)NN * 256 * 2);
  int* rowptr = (int*)alloc((size_t)(NN + 1) * sizeof(int));
  // meta block: cnt[50048 pad] | bcur[1024 pad] | ovfn[64]
  const int ZN = 50048 + 1024 + 64;
  int* meta = (int*)alloc((size_t)ZN * sizeof(int));
  int* cnt  = meta;
  int* bcur = meta + 50048;
  int* ovfn = meta + 50048 + 1024;
  int* col    = (int*)alloc((size_t)NE * sizeof(int));
  uint* pairs = (uint*)alloc((size_t)NB * BCAP * sizeof(uint));
  uint* ovf   = (uint*)alloc((size_t)OVFCAP * sizeof(uint));
  _Float16* W0s = (_Float16*)alloc(256 * 128 * 2);
  _Float16* W0n = (_Float16*)alloc(256 * 128 * 2);
  _Float16* W1s = (_Float16*)alloc(256 * 256 * 2);
  _Float16* W1n = (_Float16*)alloc(256 * 256 * 2);
  _Float16* W2s = (_Float16*)alloc(256 * 256 * 2);
  _Float16* W2n = (_Float16*)alloc(256 * 256 * 2);

  // CSR build (bucketed, privatized radix)
  k_zero<<<(ZN + 1023) / 1024, 1024, 0, stream>>>(meta, ZN);
  k_radix<<<RADIX_BLOCKS, 256, 0, stream>>>(src, dst, bcur, pairs, cnt, ovfn, ovf);
  k_countb<<<NB, 256, 0, stream>>>(bcur, pairs, cnt);
  k_scan<<<1, 1024, 0, stream>>>(cnt, rowptr);
  k_fillb<<<NB, 256, 0, stream>>>(bcur, pairs, cnt, col);
  k_fillovf<<<1, 256, 0, stream>>>(ovfn, ovf, cnt, col);

  // weight prep (fragment-major pack, fp16)
  k_wpack<<<16, 256, 0, stream>>>(Ws0, W0s, 128);
  k_wpack<<<16, 256, 0, stream>>>(Wn0, W0n, 128);
  k_wpack<<<32, 256, 0, stream>>>(Ws1, W1s, 256);
  k_wpack<<<32, 256, 0, stream>>>(Wn1, W1n, 256);
  k_wpack<<<32, 256, 0, stream>>>(Ws2, W2s, 256);
  k_wpack<<<32, 256, 0, stream>>>(Wn2, W2n, 256);

  // x -> fp16
  k_split16<<<(NN * 16 + 255) / 256, 256, 0, stream>>>(x, X16);

  const int aggGrid = (NN + 3) / 4;
  const int gemmGrid = (NN + 63) / 64;

  // layer 0 (K=128)
  k_agg_x16<<<aggGrid, 256, 0, stream>>>(x, rowptr, col, Nb);
  k_mfma16<<<gemmGrid, 256, 0, stream>>>(X16, Nb, W0s, W0n, b0, 128, H, nullptr);
  // layer 1 (K=256)
  k_agg16<<<aggGrid, 256, 0, stream>>>(H, rowptr, col, Nb);
  k_mfma16<<<gemmGrid, 256, 0, stream>>>(H, Nb, W1s, W1n, b1, 256, H, nullptr);
  // layer 2 (K=256) -> fp32 out
  k_agg16<<<aggGrid, 256, 0, stream>>>(H, rowptr, col, Nb);
  k_mfma16<<<gemmGrid, 256, 0, stream>>>(H, Nb, W2s, W2n, b2, 256, nullptr, out);
}